// Round 8
// baseline (53.124 us; speedup 1.0000x reference)
//
#include <hip/hip_runtime.h>
#include <math.h>

#define EPSF 1e-7f
// 1/(1 - SIGMA - ln(1 - SIGMA)) with SIGMA = 0.5
#define REP_INV (1.0f / 1.19314718055994530942f)
#define NBUCK 1024

// sorted record: 8 floats: x0, y0, x1p(=x1+1), y1p(=y1+1), area(+1conv), pad*3
// bound keys: float_as_int(x + 100.0f)  (always positive -> int-monotone)

__device__ __forceinline__ int bucket_of(float x, float bscale) {
    int b = (int)(x * bscale);
    return min(max(b, 0), NBUCK - 1);
}

// ---------------------------------------------------------------------------
// K0: one block. Bucket histogram + exclusive scan -> cursor; init tile bounds.
// ---------------------------------------------------------------------------
__global__ __launch_bounds__(1024) void hist_kernel(
    const float* __restrict__ pre, int* __restrict__ cursor,
    int* __restrict__ tbmin, int* __restrict__ tbmax,
    int N, int nt, float bscale)
{
    __shared__ int hist[NBUCK];
    __shared__ int scanb[NBUCK];
    int t = threadIdx.x;
    hist[t] = 0;
    __syncthreads();
    for (int i = t; i < N; i += 1024)
        atomicAdd(&hist[bucket_of(pre[(size_t)i * 4], bscale)], 1);
    __syncthreads();
    int own = hist[t];
    scanb[t] = own;
    __syncthreads();
    for (int off = 1; off < NBUCK; off <<= 1) {
        int u = (t >= off) ? scanb[t - off] : 0;
        __syncthreads();
        scanb[t] += u;
        __syncthreads();
    }
    cursor[t] = scanb[t] - own;   // exclusive offset
    if (t < nt) { tbmin[t] = 0x7fffffff; tbmax[t] = 0; }
}

// ---------------------------------------------------------------------------
// K1: scatter preds into x-sorted order; accumulate per-128-box-tile x-bounds.
// Within-bucket order is nondeterministic; pair-sum is permutation-invariant.
// ---------------------------------------------------------------------------
__global__ __launch_bounds__(256) void scatter_kernel(
    const float* __restrict__ pre, int* __restrict__ cursor,
    float* __restrict__ sB, int* __restrict__ tbmin, int* __restrict__ tbmax,
    int N, float bscale)
{
    int i = blockIdx.x * 256 + threadIdx.x;
    if (i < N) {
        float4 q = *(const float4*)(pre + (size_t)i * 4);  // x,y,w,h
        float x0 = q.x - q.z * 0.5f, y0 = q.y - q.w * 0.5f;
        float x1p = q.x + q.z * 0.5f + 1.0f, y1p = q.y + q.w * 0.5f + 1.0f;
        int dst = atomicAdd(&cursor[bucket_of(q.x, bscale)], 1);
        *(float4*)(sB + (size_t)dst * 8) = make_float4(x0, y0, x1p, y1p);
        sB[(size_t)dst * 8 + 4] = (x1p - x0) * (y1p - y0);
        int tile = dst >> 7;
        atomicMin(&tbmin[tile], __float_as_int(x0 + 100.0f));
        atomicMax(&tbmax[tile], __float_as_int(x1p + 100.0f));
    }
}

// ---------------------------------------------------------------------------
// K2: fused repbox (sorted + tile-skip) + attr/repgt (unchanged R7 body).
// ---------------------------------------------------------------------------
__global__ __launch_bounds__(256) void fused_kernel(
    const float* __restrict__ gt, const float* __restrict__ pre,
    const float* __restrict__ sB, const int* __restrict__ tbmin,
    const int* __restrict__ tbmax,
    double* __restrict__ boxP, double* __restrict__ attrP, double* __restrict__ repgtP,
    int M, int N, int nt, int nTri)
{
    __shared__ union {
        struct { float x0[512], y0[512], x1[512], y1[512], ar[512]; double red[8]; } a;
        struct { float4 rows4[128]; float rowsA[128]; double red[4]; } b;
    } sh;

    int t = threadIdx.x;
    int bid = blockIdx.x;
    int wv = t >> 6, lane = t & 63;

    if (bid < nTri) {
        // ================= repbox tile =================
        int s = bid;
        float aq = 2.0f * (float)nt + 1.0f;
        int bi = (int)((aq - sqrtf(aq * aq - 8.0f * (float)s)) * 0.5f);
        if (bi < 0) bi = 0;
        if (bi > nt - 1) bi = nt - 1;
        while (bi > 0 && (long long)bi * nt - (long long)bi * (bi - 1) / 2 > s) --bi;
        while ((long long)(bi + 1) * nt - (long long)(bi + 1) * bi / 2 <= s) ++bi;
        long long rowoff = (long long)bi * nt - (long long)bi * (bi - 1) / 2;
        int bj = bi + (int)(s - rowoff);

        // x-disjoint tile skip (scalar, block-uniform; keys int-monotone)
        if (tbmin[bj] >= tbmax[bi] || tbmin[bi] >= tbmax[bj]) {
            if (t == 0) boxP[bid] = 0.0;
            return;
        }

        int rbase = bi * 128, cbase = bj * 128;

        if (t < 128) {
            int rg = rbase + t;
            int rc = (rg < N) ? rg : 0;
            sh.b.rows4[t] = *(const float4*)(sB + (size_t)rc * 8);
            sh.b.rowsA[t] = sB[(size_t)rc * 8 + 4];
        }

        int j0 = cbase + lane, j1 = j0 + 64;
        int j0c = (j0 < N) ? j0 : 0;
        int j1c = (j1 < N) ? j1 : 0;
        float4 c0 = *(const float4*)(sB + (size_t)j0c * 8);
        float  c0a = sB[(size_t)j0c * 8 + 4];
        float4 c1 = *(const float4*)(sB + (size_t)j1c * 8);
        float  c1a = sB[(size_t)j1c * 8 + 4];
        __syncthreads();

        float sum = 0.0f;
        int r0 = wv * 32;
        bool interior = (bi < bj) && (rbase + 128 <= N) && (cbase + 128 <= N);

        if (interior) {
            #pragma unroll 4
            for (int rr = 0; rr < 32; ++rr) {
                int r = r0 + rr;
                float4 rb = sh.b.rows4[r]; float ra = sh.b.rowsA[r];
                float w0 = fmaxf(fminf(rb.z, c0.z) - fmaxf(rb.x, c0.x), 0.0f);
                float h0 = fmaxf(fminf(rb.w, c0.w) - fmaxf(rb.y, c0.y), 0.0f);
                float ov0 = w0 * h0;
                float w1 = fmaxf(fminf(rb.z, c1.z) - fmaxf(rb.x, c1.x), 0.0f);
                float h1 = fmaxf(fminf(rb.w, c1.w) - fmaxf(rb.y, c1.y), 0.0f);
                float ov1 = w1 * h1;
                if (__any(ov0 + ov1 > 0.0f)) {
                    float v0 = ov0 * __builtin_amdgcn_rcpf(ra + c0a - ov0);
                    float t0 = (v0 > 0.5f) ? (v0 - 0.5f) * REP_INV
                                           : 0.0f - __logf(fmaxf(1.0f - v0, EPSF));
                    float v1 = ov1 * __builtin_amdgcn_rcpf(ra + c1a - ov1);
                    float t1 = (v1 > 0.5f) ? (v1 - 0.5f) * REP_INV
                                           : 0.0f - __logf(fmaxf(1.0f - v1, EPSF));
                    sum += t0 + t1;
                }
            }
        } else {
            #pragma unroll 4
            for (int rr = 0; rr < 32; ++rr) {
                int r = r0 + rr;
                int ig = rbase + r;
                float4 rb = sh.b.rows4[r]; float ra = sh.b.rowsA[r];
                float w0 = fmaxf(fminf(rb.z, c0.z) - fmaxf(rb.x, c0.x), 0.0f);
                float h0 = fmaxf(fminf(rb.w, c0.w) - fmaxf(rb.y, c0.y), 0.0f);
                float ov0 = w0 * h0;
                float w1 = fmaxf(fminf(rb.z, c1.z) - fmaxf(rb.x, c1.x), 0.0f);
                float h1 = fmaxf(fminf(rb.w, c1.w) - fmaxf(rb.y, c1.y), 0.0f);
                float ov1 = w1 * h1;
                bool valid0 = (j0 > ig) && (j0 < N) && (ig < N);
                bool valid1 = (j1 > ig) && (j1 < N) && (ig < N);
                if (__any(ov0 + ov1 > 0.0f)) {
                    float v0 = ov0 * __builtin_amdgcn_rcpf(ra + c0a - ov0);
                    float t0 = (v0 > 0.5f) ? (v0 - 0.5f) * REP_INV
                                           : 0.0f - __logf(fmaxf(1.0f - v0, EPSF));
                    float v1 = ov1 * __builtin_amdgcn_rcpf(ra + c1a - ov1);
                    float t1 = (v1 > 0.5f) ? (v1 - 0.5f) * REP_INV
                                           : 0.0f - __logf(fmaxf(1.0f - v1, EPSF));
                    if (valid0) sum += t0;
                    if (valid1) sum += t1;
                }
            }
        }

        for (int off = 32; off > 0; off >>= 1) sum += __shfl_down(sum, off);
        if (lane == 0) sh.b.red[wv] = (double)sum;
        __syncthreads();
        if (t == 0) boxP[bid] = sh.b.red[0] + sh.b.red[1] + sh.b.red[2] + sh.b.red[3];

    } else {
        // ================= attr + repgt (unchanged) =================
        int abid = bid - nTri;

        for (int k = t; k < M; k += 256) {
            float4 q = *(const float4*)(gt + (size_t)k * 4);
            float x0 = q.x - q.z * 0.5f, y0 = q.y - q.w * 0.5f;
            float x1p = q.x + q.z * 0.5f + 1.0f, y1p = q.y + q.w * 0.5f + 1.0f;
            sh.a.x0[k] = x0; sh.a.y0[k] = y0;
            sh.a.x1[k] = x1p; sh.a.y1[k] = y1p;
            sh.a.ar[k] = (x1p - x0) * (y1p - y0);
        }
        if (t < 8) sh.a.red[t] = 0.0;
        __syncthreads();

        int n = abid * 4 + wv;
        if (n < N) {
            float4 q = *(const float4*)(pre + (size_t)n * 4);
            float px0 = q.x - q.z * 0.5f, py0 = q.y - q.w * 0.5f;
            float px1 = q.x + q.z * 0.5f + 1.0f, py1 = q.y + q.w * 0.5f + 1.0f;
            float pa = (px1 - px0) * (py1 - py0);

            float best1 = -1.0f; int idx1 = 0;
            for (int m = lane; m < M; m += 64) {
                float w = fmaxf(fminf(sh.a.x1[m], px1) - fmaxf(sh.a.x0[m], px0), 0.0f);
                float h = fmaxf(fminf(sh.a.y1[m], py1) - fmaxf(sh.a.y0[m], py0), 0.0f);
                float ov = w * h;
                float v = ov * __builtin_amdgcn_rcpf(fmaxf(sh.a.ar[m] + pa - ov, EPSF));
                v = fminf(fmaxf(v, EPSF), 1.0f);
                if (v > best1) { best1 = v; idx1 = m; }
            }
            for (int off = 32; off > 0; off >>= 1) {
                float bv = __shfl_xor(best1, off);
                int   bi2 = __shfl_xor(idx1, off);
                if (bv > best1 || (bv == best1 && bi2 < idx1)) { best1 = bv; idx1 = bi2; }
            }

            float best2 = -1.0f; int idx2 = 0;
            for (int m = lane; m < M; m += 64) {
                float w = fmaxf(fminf(sh.a.x1[m], px1) - fmaxf(sh.a.x0[m], px0), 0.0f);
                float h = fmaxf(fminf(sh.a.y1[m], py1) - fmaxf(sh.a.y0[m], py0), 0.0f);
                float ov = w * h;
                float v = ov * __builtin_amdgcn_rcpf(fmaxf(sh.a.ar[m] + pa - ov, EPSF));
                v = fminf(fmaxf(v, EPSF), 1.0f);
                v = (m == idx1) ? -1.0f : v;
                if (v > best2) { best2 = v; idx2 = m; }
            }
            for (int off = 32; off > 0; off >>= 1) {
                float bv = __shfl_xor(best2, off);
                int   bi2 = __shfl_xor(idx2, off);
                if (bv > best2 || (bv == best2 && bi2 < idx2)) { best2 = bv; idx2 = bi2; }
            }

            if (lane == 0) {
                float s = 0.0f, d;
                d = fabsf(px0 - sh.a.x0[idx1]); s += (d < 1.0f) ? 0.5f * d * d : d - 0.5f;
                d = fabsf(py0 - sh.a.y0[idx1]); s += (d < 1.0f) ? 0.5f * d * d : d - 0.5f;
                d = fabsf(px1 - sh.a.x1[idx1]); s += (d < 1.0f) ? 0.5f * d * d : d - 0.5f;
                d = fabsf(py1 - sh.a.y1[idx1]); s += (d < 1.0f) ? 0.5f * d * d : d - 0.5f;

                float rx0 = sh.a.x0[idx2], ry0 = sh.a.y0[idx2];
                float rx1 = sh.a.x1[idx2] - 1.0f, ry1 = sh.a.y1[idx2] - 1.0f;
                float lx = fmaxf(px0, rx0), ly = fmaxf(py0, ry0);
                float rbx = fminf(px1 - 1.0f, rx1), rby = fminf(py1 - 1.0f, ry1);
                float w = fmaxf(rbx - lx, 0.0f), h = fmaxf(rby - ly, 0.0f);
                float inter = w * h;
                float garea = fabsf(rx1 - rx0) * fabsf(ry1 - ry0);
                float iog = inter / garea;
                float rep;
                if (iog > 0.5f) rep = (iog - 0.5f) * REP_INV;
                else            rep = -logf(fmaxf(1.0f - iog, EPSF));

                sh.a.red[wv] = (double)s;
                sh.a.red[4 + wv] = (double)rep;
            }
        }
        __syncthreads();
        if (t == 0) {
            attrP[abid]  = sh.a.red[0] + sh.a.red[1] + sh.a.red[2] + sh.a.red[3];
            repgtP[abid] = sh.a.red[4] + sh.a.red[5] + sh.a.red[6] + sh.a.red[7];
        }
    }
}

// ---------------------------------------------------------------------------
// K3: finalize — one block sums the partial arrays (L2-resident).
// ---------------------------------------------------------------------------
__device__ __forceinline__ double block_sum(const double* p, int n, int t,
                                            double* sred) {
    double s = 0.0;
    for (int k = t; k < n; k += 256) s += p[k];
    for (int off = 32; off > 0; off >>= 1) s += __shfl_down(s, off);
    if ((t & 63) == 0) sred[t >> 6] = s;
    __syncthreads();
    double r = sred[0] + sred[1] + sred[2] + sred[3];
    __syncthreads();
    return r;
}

__global__ __launch_bounds__(256) void finalize_kernel(
    const double* __restrict__ boxP, int nB,
    const double* __restrict__ attrP, const double* __restrict__ repgtP, int nA,
    float* __restrict__ out, int N, long long cnt)
{
    __shared__ double sred[4];
    int t = threadIdx.x;
    double repbox = block_sum(boxP, nB, t, sred);
    double attr   = block_sum(attrP, nA, t, sred);
    double repgt  = block_sum(repgtP, nA, t, sred);
    if (t == 0) {
        out[0] = (float)(attr / (double)N + 0.5 * repgt / (double)N
                         + 0.5 * repbox / (double)cnt);
    }
}

extern "C" void kernel_launch(void* const* d_in, const int* in_sizes, int n_in,
                              void* d_out, int out_size, void* d_ws, size_t ws_size,
                              hipStream_t stream) {
    const float* gt  = (const float*)d_in[0];
    const float* pre = (const float*)d_in[1];
    int M = in_sizes[0] / 4;   // 512
    int N = in_sizes[1] / 4;   // 8192

    int nA = (N + 3) / 4;                 // 2048 attr blocks (1 wave/pred)
    int nt = (N + 127) / 128;             // 64 tiles per dim
    int nTri = nt * (nt + 1) / 2;         // 2080 upper-tri tiles

    char* ws = (char*)d_ws;
    size_t off = 0;
    double* boxP   = (double*)(ws + off); off += ((size_t)nTri * 8 + 255) / 256 * 256;
    double* attrP  = (double*)(ws + off); off += ((size_t)nA * 8 + 255) / 256 * 256;
    double* repgtP = (double*)(ws + off); off += ((size_t)nA * 8 + 255) / 256 * 256;
    float*  sB     = (float*)(ws + off);  off += ((size_t)N * 8 * 4 + 255) / 256 * 256;
    int*    cursor = (int*)(ws + off);    off += ((size_t)NBUCK * 4 + 255) / 256 * 256;
    int*    tbmin  = (int*)(ws + off);    off += ((size_t)nt * 4 + 255) / 256 * 256;
    int*    tbmax  = (int*)(ws + off);
    float*  out    = (float*)d_out;

    float bscale = (float)NBUCK / 640.0f;
    hist_kernel<<<1, 1024, 0, stream>>>(pre, cursor, tbmin, tbmax, N, nt, bscale);

    scatter_kernel<<<(N + 255) / 256, 256, 0, stream>>>(pre, cursor, sB, tbmin, tbmax, N, bscale);

    fused_kernel<<<nTri + nA, 256, 0, stream>>>(gt, pre, sB, tbmin, tbmax,
                                                boxP, attrP, repgtP, M, N, nt, nTri);

    long long cnt = (long long)N * (N - 1) / 2;
    finalize_kernel<<<1, 256, 0, stream>>>(boxP, nTri, attrP, repgtP, nA, out, N, cnt);
}